// Round 1
// baseline (13691.064 us; speedup 1.0000x reference)
//
#include <hip/hip_runtime.h>
#include <cstdint>
#include <cstddef>

#define NN 50000
#define EE 1600000

// ---------------- edge weight: mean over 8 attrs ----------------
__global__ __launch_bounds__(256) void ew_kernel(const float* __restrict__ ea,
                                                 float* __restrict__ ew, int E) {
    int e = blockIdx.x * 256 + threadIdx.x;
    if (e >= E) return;
    const float4* p = (const float4*)(ea + (size_t)e * 8);
    float4 a = p[0], b = p[1];
    ew[e] = (a.x + a.y + a.z + a.w + b.x + b.y + b.z + b.w) * 0.125f;
}

// ---------------- scatter-aggregate: agg[dst] += ew * h[src] ----------------
// C channels per node; C/4 lanes per edge, each lane does a float4 gather +
// 4 fp32 atomicAdds. Node rows are contiguous -> gather/scatter coalesced per edge.
template <int C, bool HASW>
__global__ __launch_bounds__(256) void scatter_kernel(
    const float* __restrict__ h, const int* __restrict__ src,
    const int* __restrict__ dst, const float* __restrict__ ew,
    float* __restrict__ agg, int E)
{
    constexpr int LPE = C / 4;               // 32 (C=128) or 64 (C=256)
    int tid  = blockIdx.x * 256 + threadIdx.x;
    int e    = tid / LPE;
    int lane = tid % LPE;
    if (e >= E) return;
    int s = src[e], d = dst[e];
    if ((unsigned)s >= NN || (unsigned)d >= NN) return;  // defensive: bad index dtype fails softly
    float w = HASW ? ew[e] : 1.0f;
    float4 v = *((const float4*)(h + (size_t)s * C) + lane);
    float* ap = agg + (size_t)d * C + lane * 4;
    atomicAdd(ap + 0, v.x * w);
    atomicAdd(ap + 1, v.y * w);
    atomicAdd(ap + 2, v.z * w);
    atomicAdd(ap + 3, v.w * w);
}

// ---------------- out = A[M,CIN] @ W[256,CIN]^T + bias (+BN+ReLU) ----------------
// 128x128 tile, BK=16, 256 threads, 8x8 microtile per thread.
template <int CIN, bool FUSE>
__global__ __launch_bounds__(256) void matmul_kernel(
    const float* __restrict__ A, const float* __restrict__ W,
    const float* __restrict__ bias,
    const float* __restrict__ gamma, const float* __restrict__ beta,
    const float* __restrict__ mean, const float* __restrict__ var,
    float* __restrict__ out, int M)
{
    __shared__ float As[16][132];  // row stride 132 floats = 528B, 16B-aligned
    __shared__ float Bs[16][132];
    const int tid  = threadIdx.x;
    const int row0 = blockIdx.x * 128;
    const int col0 = blockIdx.y * 128;
    const int kq = tid & 3;    // k-quad for loads
    const int rj = tid >> 2;   // 0..63: row / col-of-W for loads
    const int tm = tid & 15;   // microtile row group
    const int tn = tid >> 4;   // microtile col group

    float acc[8][8];
    #pragma unroll
    for (int i = 0; i < 8; i++)
        #pragma unroll
        for (int j = 0; j < 8; j++) acc[i][j] = 0.f;

    for (int k0 = 0; k0 < CIN; k0 += 16) {
        float4 av[2], bv[2];
        #pragma unroll
        for (int t = 0; t < 2; t++) {
            int row = t * 64 + rj;
            int g = row0 + row;
            av[t] = make_float4(0.f, 0.f, 0.f, 0.f);
            if (g < M)
                av[t] = *(const float4*)(A + (size_t)g * CIN + k0 + kq * 4);
            bv[t] = *(const float4*)(W + (size_t)(col0 + row) * CIN + k0 + kq * 4);
        }
        __syncthreads();  // prior compute done before overwriting LDS
        #pragma unroll
        for (int t = 0; t < 2; t++) {
            int row = t * 64 + rj;
            As[kq * 4 + 0][row] = av[t].x;
            As[kq * 4 + 1][row] = av[t].y;
            As[kq * 4 + 2][row] = av[t].z;
            As[kq * 4 + 3][row] = av[t].w;
            Bs[kq * 4 + 0][row] = bv[t].x;
            Bs[kq * 4 + 1][row] = bv[t].y;
            Bs[kq * 4 + 2][row] = bv[t].z;
            Bs[kq * 4 + 3][row] = bv[t].w;
        }
        __syncthreads();
        #pragma unroll
        for (int k = 0; k < 16; k++) {
            float4 x0 = *(const float4*)&As[k][tm * 8];
            float4 x1 = *(const float4*)&As[k][tm * 8 + 4];
            float4 y0 = *(const float4*)&Bs[k][tn * 8];
            float4 y1 = *(const float4*)&Bs[k][tn * 8 + 4];
            float aa[8] = {x0.x, x0.y, x0.z, x0.w, x1.x, x1.y, x1.z, x1.w};
            float bb[8] = {y0.x, y0.y, y0.z, y0.w, y1.x, y1.y, y1.z, y1.w};
            #pragma unroll
            for (int i = 0; i < 8; i++)
                #pragma unroll
                for (int j = 0; j < 8; j++)
                    acc[i][j] += aa[i] * bb[j];
        }
    }

    // epilogue: +bias, optional BN(eval)+ReLU, float4 stores
    float cb[8], cmu[8], cinv[8], cbe[8];
    #pragma unroll
    for (int j = 0; j < 8; j++) {
        int c = col0 + tn * 8 + j;
        cb[j] = bias[c];
        if (FUSE) {
            cmu[j]  = mean[c];
            cinv[j] = gamma[c] * rsqrtf(var[c] + 1e-5f);
            cbe[j]  = beta[c];
        }
    }
    #pragma unroll
    for (int i = 0; i < 8; i++) {
        int g = row0 + tm * 8 + i;
        if (g >= M) continue;
        float o[8];
        #pragma unroll
        for (int j = 0; j < 8; j++) {
            float v = acc[i][j] + cb[j];
            if (FUSE) {
                v = (v - cmu[j]) * cinv[j] + cbe[j];
                v = v > 0.f ? v : 0.f;
            }
            o[j] = v;
        }
        float* po = out + (size_t)g * 256 + col0 + tn * 8;
        *(float4*)po       = make_float4(o[0], o[1], o[2], o[3]);
        *(float4*)(po + 4) = make_float4(o[4], o[5], o[6], o[7]);
    }
}

extern "C" void kernel_launch(void* const* d_in, const int* in_sizes, int n_in,
                              void* d_out, int out_size, void* d_ws, size_t ws_size,
                              hipStream_t stream) {
    const float* x   = (const float*)d_in[0];
    const int*   ei  = (const int*)d_in[1];   // [2, E] int32 (JAX non-x64 demotes i64)
    const float* ea  = (const float*)d_in[2];
    const float* W1  = (const float*)d_in[3];
    const float* b1  = (const float*)d_in[4];
    const float* g1  = (const float*)d_in[5];
    const float* be1 = (const float*)d_in[6];
    const float* m1  = (const float*)d_in[7];
    const float* v1  = (const float*)d_in[8];
    const float* W2  = (const float*)d_in[9];
    const float* b2  = (const float*)d_in[10];
    const float* g2  = (const float*)d_in[11];
    const float* be2 = (const float*)d_in[12];
    const float* m2  = (const float*)d_in[13];
    const float* v2  = (const float*)d_in[14];
    const float* W3  = (const float*)d_in[15];
    const float* b3  = (const float*)d_in[16];

    const int* src = ei;
    const int* dst = ei + EE;

    // workspace layout: ew[E] | agg[N*256] | h[N*256]  (~108.8 MB)
    float* ew  = (float*)d_ws;
    float* agg = ew + EE;
    float* h   = agg + (size_t)NN * 256;
    float* out = (float*)d_out;

    const int mtiles = (NN + 127) / 128;  // 391

    // edge weights (shared by layers 1 & 2)
    ew_kernel<<<(EE + 255) / 256, 256, 0, stream>>>(ea, ew, EE);

    // ---- layer 1: aggregate x (C=128) -> matmul W1 + BN1 + ReLU -> h ----
    hipMemsetAsync(agg, 0, (size_t)NN * 128 * sizeof(float), stream);
    scatter_kernel<128, true><<<EE * 32 / 256, 256, 0, stream>>>(x, src, dst, ew, agg, EE);
    matmul_kernel<128, true><<<dim3(mtiles, 2), 256, 0, stream>>>(
        agg, W1, b1, g1, be1, m1, v1, h, NN);

    // ---- layer 2: aggregate h (C=256) -> matmul W2 + BN2 + ReLU -> h ----
    hipMemsetAsync(agg, 0, (size_t)NN * 256 * sizeof(float), stream);
    scatter_kernel<256, true><<<EE * 64 / 256, 256, 0, stream>>>(h, src, dst, ew, agg, EE);
    matmul_kernel<256, true><<<dim3(mtiles, 2), 256, 0, stream>>>(
        agg, W2, b2, g2, be2, m2, v2, h, NN);

    // ---- layer 3: aggregate h (C=256, no edge weight) -> matmul W3 -> out ----
    hipMemsetAsync(agg, 0, (size_t)NN * 256 * sizeof(float), stream);
    scatter_kernel<256, false><<<EE * 64 / 256, 256, 0, stream>>>(h, src, dst, nullptr, agg, EE);
    matmul_kernel<256, false><<<dim3(mtiles, 2), 256, 0, stream>>>(
        agg, W3, b3, nullptr, nullptr, nullptr, nullptr, out, NN);
}

// Round 2
// 1307.029 us; speedup vs baseline: 10.4750x; 10.4750x over previous
//
#include <hip/hip_runtime.h>
#include <cstdint>
#include <cstddef>

#define NN 50000
#define EE 1600000

// ---------------- edge weight: mean over 8 attrs ----------------
__global__ __launch_bounds__(256) void ew_kernel(const float* __restrict__ ea,
                                                 float* __restrict__ ew, int E) {
    int e = blockIdx.x * 256 + threadIdx.x;
    if (e >= E) return;
    const float4* p = (const float4*)(ea + (size_t)e * 8);
    float4 a = p[0], b = p[1];
    ew[e] = (a.x + a.y + a.z + a.w + b.x + b.y + b.z + b.w) * 0.125f;
}

// ---------------- CSR build: histogram -> scan -> bin ----------------
__global__ __launch_bounds__(256) void hist_kernel(const int* __restrict__ dst,
                                                   int* __restrict__ deg, int E) {
    int e = blockIdx.x * 256 + threadIdx.x;
    if (e >= E) return;
    int d = dst[e];
    if ((unsigned)d < NN) atomicAdd(&deg[d], 1);
}

// single block, 256 threads; deg may alias cursor (read-before-write per elem)
__global__ __launch_bounds__(256) void scan_kernel(const int* __restrict__ deg,
                                                   int* __restrict__ rowptr,
                                                   int* __restrict__ cursor) {
    constexpr int CH = (NN + 255) / 256;  // 196
    __shared__ int sums[256];
    int t = threadIdx.x;
    int lo = t * CH, hi = min(lo + CH, NN);
    int s = 0;
    for (int i = lo; i < hi; i++) s += deg[i];
    sums[t] = s;
    __syncthreads();
    if (t == 0) {
        int acc = 0;
        for (int i = 0; i < 256; i++) { int v = sums[i]; sums[i] = acc; acc += v; }
    }
    __syncthreads();
    int acc = sums[t];
    for (int i = lo; i < hi; i++) {
        int d = deg[i];          // save before cursor write (aliasing)
        rowptr[i] = acc;
        cursor[i] = acc;
        acc += d;
    }
    if (hi == NN) rowptr[NN] = acc;
}

__global__ __launch_bounds__(256) void bin_kernel(
    const int* __restrict__ src, const int* __restrict__ dst,
    const float* __restrict__ ew, int* __restrict__ cursor,
    int* __restrict__ src_sorted, float* __restrict__ w_sorted, int E)
{
    int e = blockIdx.x * 256 + threadIdx.x;
    if (e >= E) return;
    int d = dst[e], s = src[e];
    if ((unsigned)d >= NN || (unsigned)s >= NN) return;
    int p = atomicAdd(&cursor[d], 1);
    src_sorted[p] = s;
    w_sorted[p] = ew[e];
}

// ---------------- gather-aggregate: agg[i] = sum_{e in CSR[i]} w_e * h[src_e] ----
// One wave (64 lanes) per destination node. C=256: float4/lane; C=128: float2/lane.
template <int C, bool HASW>
__global__ __launch_bounds__(256) void gather_kernel(
    const float* __restrict__ h, const int* __restrict__ rowptr,
    const int* __restrict__ srcs, const float* __restrict__ ws,
    float* __restrict__ agg)
{
    int node = blockIdx.x * 4 + (threadIdx.x >> 6);
    int lane = threadIdx.x & 63;
    if (node >= NN) return;
    int beg = rowptr[node], end = rowptr[node + 1];

    if (C == 256) {
        const float4* hp = (const float4*)h;
        float4 acc = make_float4(0.f, 0.f, 0.f, 0.f);
        int j = beg;
        for (; j + 1 < end; j += 2) {
            int s0 = srcs[j], s1 = srcs[j + 1];
            float w0 = HASW ? ws[j] : 1.f;
            float w1 = HASW ? ws[j + 1] : 1.f;
            float4 v0 = hp[(size_t)s0 * 64 + lane];
            float4 v1 = hp[(size_t)s1 * 64 + lane];
            acc.x += w0 * v0.x + w1 * v1.x;
            acc.y += w0 * v0.y + w1 * v1.y;
            acc.z += w0 * v0.z + w1 * v1.z;
            acc.w += w0 * v0.w + w1 * v1.w;
        }
        if (j < end) {
            int s0 = srcs[j];
            float w0 = HASW ? ws[j] : 1.f;
            float4 v0 = hp[(size_t)s0 * 64 + lane];
            acc.x += w0 * v0.x; acc.y += w0 * v0.y;
            acc.z += w0 * v0.z; acc.w += w0 * v0.w;
        }
        ((float4*)agg)[(size_t)node * 64 + lane] = acc;
    } else {  // C == 128
        const float2* hp = (const float2*)h;
        float2 acc = make_float2(0.f, 0.f);
        int j = beg;
        for (; j + 1 < end; j += 2) {
            int s0 = srcs[j], s1 = srcs[j + 1];
            float w0 = HASW ? ws[j] : 1.f;
            float w1 = HASW ? ws[j + 1] : 1.f;
            float2 v0 = hp[(size_t)s0 * 64 + lane];
            float2 v1 = hp[(size_t)s1 * 64 + lane];
            acc.x += w0 * v0.x + w1 * v1.x;
            acc.y += w0 * v0.y + w1 * v1.y;
        }
        if (j < end) {
            int s0 = srcs[j];
            float w0 = HASW ? ws[j] : 1.f;
            float2 v0 = hp[(size_t)s0 * 64 + lane];
            acc.x += w0 * v0.x; acc.y += w0 * v0.y;
        }
        ((float2*)agg)[(size_t)node * 64 + lane] = acc;
    }
}

// ---------------- out = A[M,CIN] @ W[256,CIN]^T + bias (+BN+ReLU) ----------------
// 128x128 tile, BK=16, 256 threads, 8x8 microtile per thread.
template <int CIN, bool FUSE>
__global__ __launch_bounds__(256) void matmul_kernel(
    const float* __restrict__ A, const float* __restrict__ W,
    const float* __restrict__ bias,
    const float* __restrict__ gamma, const float* __restrict__ beta,
    const float* __restrict__ mean, const float* __restrict__ var,
    float* __restrict__ out, int M)
{
    __shared__ float As[16][132];
    __shared__ float Bs[16][132];
    const int tid  = threadIdx.x;
    const int row0 = blockIdx.x * 128;
    const int col0 = blockIdx.y * 128;
    const int kq = tid & 3;
    const int rj = tid >> 2;
    const int tm = tid & 15;
    const int tn = tid >> 4;

    float acc[8][8];
    #pragma unroll
    for (int i = 0; i < 8; i++)
        #pragma unroll
        for (int j = 0; j < 8; j++) acc[i][j] = 0.f;

    for (int k0 = 0; k0 < CIN; k0 += 16) {
        float4 av[2], bv[2];
        #pragma unroll
        for (int t = 0; t < 2; t++) {
            int row = t * 64 + rj;
            int g = row0 + row;
            av[t] = make_float4(0.f, 0.f, 0.f, 0.f);
            if (g < M)
                av[t] = *(const float4*)(A + (size_t)g * CIN + k0 + kq * 4);
            bv[t] = *(const float4*)(W + (size_t)(col0 + row) * CIN + k0 + kq * 4);
        }
        __syncthreads();
        #pragma unroll
        for (int t = 0; t < 2; t++) {
            int row = t * 64 + rj;
            As[kq * 4 + 0][row] = av[t].x;
            As[kq * 4 + 1][row] = av[t].y;
            As[kq * 4 + 2][row] = av[t].z;
            As[kq * 4 + 3][row] = av[t].w;
            Bs[kq * 4 + 0][row] = bv[t].x;
            Bs[kq * 4 + 1][row] = bv[t].y;
            Bs[kq * 4 + 2][row] = bv[t].z;
            Bs[kq * 4 + 3][row] = bv[t].w;
        }
        __syncthreads();
        #pragma unroll
        for (int k = 0; k < 16; k++) {
            float4 x0 = *(const float4*)&As[k][tm * 8];
            float4 x1 = *(const float4*)&As[k][tm * 8 + 4];
            float4 y0 = *(const float4*)&Bs[k][tn * 8];
            float4 y1 = *(const float4*)&Bs[k][tn * 8 + 4];
            float aa[8] = {x0.x, x0.y, x0.z, x0.w, x1.x, x1.y, x1.z, x1.w};
            float bb[8] = {y0.x, y0.y, y0.z, y0.w, y1.x, y1.y, y1.z, y1.w};
            #pragma unroll
            for (int i = 0; i < 8; i++)
                #pragma unroll
                for (int j = 0; j < 8; j++)
                    acc[i][j] += aa[i] * bb[j];
        }
    }

    float cb[8], cmu[8], cinv[8], cbe[8];
    #pragma unroll
    for (int j = 0; j < 8; j++) {
        int c = col0 + tn * 8 + j;
        cb[j] = bias[c];
        if (FUSE) {
            cmu[j]  = mean[c];
            cinv[j] = gamma[c] * rsqrtf(var[c] + 1e-5f);
            cbe[j]  = beta[c];
        }
    }
    #pragma unroll
    for (int i = 0; i < 8; i++) {
        int g = row0 + tm * 8 + i;
        if (g >= M) continue;
        float o[8];
        #pragma unroll
        for (int j = 0; j < 8; j++) {
            float v = acc[i][j] + cb[j];
            if (FUSE) {
                v = (v - cmu[j]) * cinv[j] + cbe[j];
                v = v > 0.f ? v : 0.f;
            }
            o[j] = v;
        }
        float* po = out + (size_t)g * 256 + col0 + tn * 8;
        *(float4*)po       = make_float4(o[0], o[1], o[2], o[3]);
        *(float4*)(po + 4) = make_float4(o[4], o[5], o[6], o[7]);
    }
}

extern "C" void kernel_launch(void* const* d_in, const int* in_sizes, int n_in,
                              void* d_out, int out_size, void* d_ws, size_t ws_size,
                              hipStream_t stream) {
    const float* x   = (const float*)d_in[0];
    const int*   ei  = (const int*)d_in[1];   // [2, E] int32
    const float* ea  = (const float*)d_in[2];
    const float* W1  = (const float*)d_in[3];
    const float* b1  = (const float*)d_in[4];
    const float* g1  = (const float*)d_in[5];
    const float* be1 = (const float*)d_in[6];
    const float* m1  = (const float*)d_in[7];
    const float* v1  = (const float*)d_in[8];
    const float* W2  = (const float*)d_in[9];
    const float* b2  = (const float*)d_in[10];
    const float* g2  = (const float*)d_in[11];
    const float* be2 = (const float*)d_in[12];
    const float* m2  = (const float*)d_in[13];
    const float* v2  = (const float*)d_in[14];
    const float* W3  = (const float*)d_in[15];
    const float* b3  = (const float*)d_in[16];

    const int* src = ei;
    const int* dst = ei + EE;

    // ws layout: ew[E] | rowptr[N+1] | cursor[N] | src_sorted[E] | w_sorted[E] | agg[N*256] | h[N*256]
    float* ew        = (float*)d_ws;
    int*   rowptr    = (int*)(ew + EE);
    int*   cursor    = rowptr + (NN + 1) + 3;           // keep 16B alignment
    int*   src_sorted= cursor + NN + 2;
    float* w_sorted  = (float*)(src_sorted + EE);
    float* agg       = w_sorted + EE;
    float* h         = agg + (size_t)NN * 256;
    float* out       = (float*)d_out;

    const int eblocks = (EE + 255) / 256;
    const int gblocks = (NN + 3) / 4;
    const int mtiles  = (NN + 127) / 128;

    // edge weights (layers 1 & 2)
    ew_kernel<<<eblocks, 256, 0, stream>>>(ea, ew, EE);

    // CSR build (cursor doubles as deg histogram)
    hipMemsetAsync(cursor, 0, NN * sizeof(int), stream);
    hist_kernel<<<eblocks, 256, 0, stream>>>(dst, cursor, EE);
    scan_kernel<<<1, 256, 0, stream>>>(cursor, rowptr, cursor);
    bin_kernel<<<eblocks, 256, 0, stream>>>(src, dst, ew, cursor, src_sorted, w_sorted, EE);

    // ---- layer 1: aggregate x (C=128) -> matmul W1 + BN1 + ReLU -> h ----
    gather_kernel<128, true><<<gblocks, 256, 0, stream>>>(x, rowptr, src_sorted, w_sorted, agg);
    matmul_kernel<128, true><<<dim3(mtiles, 2), 256, 0, stream>>>(
        agg, W1, b1, g1, be1, m1, v1, h, NN);

    // ---- layer 2: aggregate h (C=256) -> matmul W2 + BN2 + ReLU -> h ----
    gather_kernel<256, true><<<gblocks, 256, 0, stream>>>(h, rowptr, src_sorted, w_sorted, agg);
    matmul_kernel<256, true><<<dim3(mtiles, 2), 256, 0, stream>>>(
        agg, W2, b2, g2, be2, m2, v2, h, NN);

    // ---- layer 3: aggregate h (C=256, no edge weight) -> matmul W3 -> out ----
    gather_kernel<256, false><<<gblocks, 256, 0, stream>>>(h, rowptr, src_sorted, nullptr, agg);
    matmul_kernel<256, false><<<dim3(mtiles, 2), 256, 0, stream>>>(
        agg, W3, b3, nullptr, nullptr, nullptr, nullptr, out, NN);
}

// Round 3
// 902.798 us; speedup vs baseline: 15.1651x; 1.4478x over previous
//
#include <hip/hip_runtime.h>
#include <cstdint>
#include <cstddef>

#define NN 50000
#define EE 1600000

typedef __attribute__((ext_vector_type(8))) short short8;
typedef __attribute__((ext_vector_type(4))) float float4v;

__device__ __forceinline__ float bf2f(unsigned short u) {
    union { unsigned int i; float f; } v; v.i = ((unsigned int)u) << 16; return v.f;
}
__device__ __forceinline__ unsigned short f2bf(float f) {
    union { float f; unsigned int i; } v; v.f = f;
    unsigned int r = v.i + 0x7FFF + ((v.i >> 16) & 1);   // RNE
    return (unsigned short)(r >> 16);
}

// ---------------- edge weight: mean over 8 attrs ----------------
__global__ __launch_bounds__(256) void ew_kernel(const float* __restrict__ ea,
                                                 float* __restrict__ ew, int E) {
    int e = blockIdx.x * 256 + threadIdx.x;
    if (e >= E) return;
    const float4* p = (const float4*)(ea + (size_t)e * 8);
    float4 a = p[0], b = p[1];
    ew[e] = (a.x + a.y + a.z + a.w + b.x + b.y + b.z + b.w) * 0.125f;
}

// ---------------- fp32 -> bf16 convert ----------------
__global__ __launch_bounds__(256) void cvt_kernel(const float* __restrict__ in,
                                                  unsigned short* __restrict__ out, int n) {
    int i = (blockIdx.x * 256 + threadIdx.x) * 4;
    if (i + 3 >= n) {
        for (int k = i; k < n; k++) out[k] = f2bf(in[k]);
        return;
    }
    float4 v = *(const float4*)(in + i);
    ushort4 o;
    o.x = f2bf(v.x); o.y = f2bf(v.y); o.z = f2bf(v.z); o.w = f2bf(v.w);
    *(ushort4*)(out + i) = o;
}

// ---------------- CSR build: histogram -> scan -> bin ----------------
__global__ __launch_bounds__(256) void hist_kernel(const int* __restrict__ dst,
                                                   int* __restrict__ deg, int E) {
    int e = blockIdx.x * 256 + threadIdx.x;
    if (e >= E) return;
    int d = dst[e];
    if ((unsigned)d < NN) atomicAdd(&deg[d], 1);
}

__global__ __launch_bounds__(256) void scan_kernel(const int* __restrict__ deg,
                                                   int* __restrict__ rowptr,
                                                   int* __restrict__ cursor) {
    constexpr int CH = (NN + 255) / 256;
    __shared__ int sums[256];
    int t = threadIdx.x;
    int lo = t * CH, hi = min(lo + CH, NN);
    int s = 0;
    for (int i = lo; i < hi; i++) s += deg[i];
    sums[t] = s;
    __syncthreads();
    if (t == 0) {
        int acc = 0;
        for (int i = 0; i < 256; i++) { int v = sums[i]; sums[i] = acc; acc += v; }
    }
    __syncthreads();
    int acc = sums[t];
    for (int i = lo; i < hi; i++) {
        int d = deg[i];
        rowptr[i] = acc;
        cursor[i] = acc;
        acc += d;
    }
    if (hi == NN) rowptr[NN] = acc;
}

__global__ __launch_bounds__(256) void bin_kernel(
    const int* __restrict__ src, const int* __restrict__ dst,
    const float* __restrict__ ew, int* __restrict__ cursor,
    int* __restrict__ src_sorted, float* __restrict__ w_sorted, int E)
{
    int e = blockIdx.x * 256 + threadIdx.x;
    if (e >= E) return;
    int d = dst[e], s = src[e];
    if ((unsigned)d >= NN || (unsigned)s >= NN) return;
    int p = atomicAdd(&cursor[d], 1);
    src_sorted[p] = s;
    w_sorted[p] = ew[e];
}

// ---------------- gather-aggregate (bf16 in, fp32 acc, bf16 out) ----------------
// One wave per destination node. C=256: ushort4/lane; C=128: ushort2/lane.
template <int C, bool HASW>
__global__ __launch_bounds__(256) void gather_bf(
    const unsigned short* __restrict__ h, const int* __restrict__ rowptr,
    const int* __restrict__ srcs, const float* __restrict__ ws,
    unsigned short* __restrict__ agg)
{
    int node = blockIdx.x * 4 + (threadIdx.x >> 6);
    int lane = threadIdx.x & 63;
    if (node >= NN) return;
    int beg = rowptr[node], end = rowptr[node + 1];

    if (C == 256) {
        float a0 = 0.f, a1 = 0.f, a2 = 0.f, a3 = 0.f;
        int j = beg;
        for (; j + 1 < end; j += 2) {
            int s0 = srcs[j], s1 = srcs[j + 1];
            float w0 = HASW ? ws[j] : 1.f;
            float w1 = HASW ? ws[j + 1] : 1.f;
            ushort4 v0 = *(const ushort4*)(h + (size_t)s0 * 256 + lane * 4);
            ushort4 v1 = *(const ushort4*)(h + (size_t)s1 * 256 + lane * 4);
            a0 += w0 * bf2f(v0.x) + w1 * bf2f(v1.x);
            a1 += w0 * bf2f(v0.y) + w1 * bf2f(v1.y);
            a2 += w0 * bf2f(v0.z) + w1 * bf2f(v1.z);
            a3 += w0 * bf2f(v0.w) + w1 * bf2f(v1.w);
        }
        if (j < end) {
            int s0 = srcs[j];
            float w0 = HASW ? ws[j] : 1.f;
            ushort4 v0 = *(const ushort4*)(h + (size_t)s0 * 256 + lane * 4);
            a0 += w0 * bf2f(v0.x); a1 += w0 * bf2f(v0.y);
            a2 += w0 * bf2f(v0.z); a3 += w0 * bf2f(v0.w);
        }
        ushort4 o;
        o.x = f2bf(a0); o.y = f2bf(a1); o.z = f2bf(a2); o.w = f2bf(a3);
        *(ushort4*)(agg + (size_t)node * 256 + lane * 4) = o;
    } else {  // C == 128
        float a0 = 0.f, a1 = 0.f;
        int j = beg;
        for (; j + 1 < end; j += 2) {
            int s0 = srcs[j], s1 = srcs[j + 1];
            float w0 = HASW ? ws[j] : 1.f;
            float w1 = HASW ? ws[j + 1] : 1.f;
            ushort2 v0 = *(const ushort2*)(h + (size_t)s0 * 128 + lane * 2);
            ushort2 v1 = *(const ushort2*)(h + (size_t)s1 * 128 + lane * 2);
            a0 += w0 * bf2f(v0.x) + w1 * bf2f(v1.x);
            a1 += w0 * bf2f(v0.y) + w1 * bf2f(v1.y);
        }
        if (j < end) {
            int s0 = srcs[j];
            float w0 = HASW ? ws[j] : 1.f;
            ushort2 v0 = *(const ushort2*)(h + (size_t)s0 * 128 + lane * 2);
            a0 += w0 * bf2f(v0.x); a1 += w0 * bf2f(v0.y);
        }
        ushort2 o;
        o.x = f2bf(a0); o.y = f2bf(a1);
        *(ushort2*)(agg + (size_t)node * 128 + lane * 2) = o;
    }
}

// ---------------- MFMA GEMM: out[M,256] = A[M,CIN](bf16) @ W[256,CIN](bf16)^T ----
// 256 thr = 4 waves in 2x2; each wave computes 64x64 via 4x4 grid of 16x16x32 MFMA.
// No LDS: A frags are contiguous 16B row-segment loads (A-layout m=lane&15,
// k=quad*8+j); W (128KB bf16) is L2-resident, loaded the same way.
// MODE 0: +bias, fp32 out. MODE 1: +bias, BN, ReLU, bf16 out.
template <int CIN, int MODE>
__global__ __launch_bounds__(256) void mm_mfma(
    const unsigned short* __restrict__ A, const unsigned short* __restrict__ W,
    const float* __restrict__ bias,
    const float* __restrict__ gamma, const float* __restrict__ beta,
    const float* __restrict__ mean, const float* __restrict__ var,
    void* __restrict__ out, int M)
{
    const int lane = threadIdx.x & 63;
    const int wave = threadIdx.x >> 6;
    const int quad = lane >> 4;
    const int l16  = lane & 15;
    const int row0 = blockIdx.x * 128 + (wave & 1) * 64;
    const int col0 = blockIdx.y * 128 + (wave >> 1) * 64;

    float4v acc[4][4] = {};

    for (int k0 = 0; k0 < CIN; k0 += 32) {
        const int ka = k0 + quad * 8;
        short8 af[4], bf[4];
        #pragma unroll
        for (int i = 0; i < 4; i++) {
            int r = row0 + i * 16 + l16;
            af[i] = (r < M) ? *(const short8*)(A + (size_t)r * CIN + ka) : (short8)0;
            bf[i] = *(const short8*)(W + (size_t)(col0 + i * 16 + l16) * CIN + ka);
        }
        #pragma unroll
        for (int mi = 0; mi < 4; mi++)
            #pragma unroll
            for (int ni = 0; ni < 4; ni++)
                acc[mi][ni] = __builtin_amdgcn_mfma_f32_16x16x32_bf16(
                    af[mi], bf[ni], acc[mi][ni], 0, 0, 0);
    }

    float cb[4], cmu[4], cinv[4], cbe[4];
    #pragma unroll
    for (int ni = 0; ni < 4; ni++) {
        int gc = col0 + ni * 16 + l16;
        cb[ni] = bias[gc];
        if (MODE == 1) {
            cmu[ni]  = mean[gc];
            cinv[ni] = gamma[gc] * rsqrtf(var[gc] + 1e-5f);
            cbe[ni]  = beta[gc];
        }
    }
    #pragma unroll
    for (int mi = 0; mi < 4; mi++) {
        #pragma unroll
        for (int reg = 0; reg < 4; reg++) {
            int gr = row0 + mi * 16 + quad * 4 + reg;
            if (gr >= M) continue;
            #pragma unroll
            for (int ni = 0; ni < 4; ni++) {
                int gc = col0 + ni * 16 + l16;
                float v = acc[mi][ni][reg] + cb[ni];
                if (MODE == 1) {
                    v = (v - cmu[ni]) * cinv[ni] + cbe[ni];
                    v = fmaxf(v, 0.f);
                    ((unsigned short*)out)[(size_t)gr * 256 + gc] = f2bf(v);
                } else {
                    ((float*)out)[(size_t)gr * 256 + gc] = v;
                }
            }
        }
    }
}

extern "C" void kernel_launch(void* const* d_in, const int* in_sizes, int n_in,
                              void* d_out, int out_size, void* d_ws, size_t ws_size,
                              hipStream_t stream) {
    const float* x   = (const float*)d_in[0];
    const int*   ei  = (const int*)d_in[1];   // [2, E] int32
    const float* ea  = (const float*)d_in[2];
    const float* W1  = (const float*)d_in[3];
    const float* b1  = (const float*)d_in[4];
    const float* g1  = (const float*)d_in[5];
    const float* be1 = (const float*)d_in[6];
    const float* m1  = (const float*)d_in[7];
    const float* v1  = (const float*)d_in[8];
    const float* W2  = (const float*)d_in[9];
    const float* b2  = (const float*)d_in[10];
    const float* g2  = (const float*)d_in[11];
    const float* be2 = (const float*)d_in[12];
    const float* m2  = (const float*)d_in[13];
    const float* v2  = (const float*)d_in[14];
    const float* W3  = (const float*)d_in[15];
    const float* b3  = (const float*)d_in[16];

    const int* src = ei;
    const int* dst = ei + EE;

    // workspace carve-up (256B-aligned segments)
    char* p = (char*)d_ws;
    auto alloc = [&](size_t bytes) { char* r = p; p += (bytes + 255) & ~255ULL; return r; };
    float*          ew        = (float*)alloc(EE * 4);
    int*            rowptr    = (int*)alloc((NN + 1) * 4);
    int*            cursor    = (int*)alloc(NN * 4);
    int*            src_sorted= (int*)alloc(EE * 4);
    float*          w_sorted  = (float*)alloc(EE * 4);
    unsigned short* xb        = (unsigned short*)alloc((size_t)NN * 128 * 2);
    unsigned short* W1b       = (unsigned short*)alloc(256 * 128 * 2);
    unsigned short* W2b       = (unsigned short*)alloc(256 * 256 * 2);
    unsigned short* W3b       = (unsigned short*)alloc(256 * 256 * 2);
    unsigned short* agg       = (unsigned short*)alloc((size_t)NN * 256 * 2);
    unsigned short* hbuf      = (unsigned short*)alloc((size_t)NN * 256 * 2);
    float*          out       = (float*)d_out;

    const int eblocks = (EE + 255) / 256;
    const int gblocks = (NN + 3) / 4;
    const int mtiles  = (NN + 127) / 128;

    // edge weights + input/weight converts
    ew_kernel<<<eblocks, 256, 0, stream>>>(ea, ew, EE);
    cvt_kernel<<<(NN * 128 / 4 + 255) / 256, 256, 0, stream>>>(x, xb, NN * 128);
    cvt_kernel<<<(256 * 128 / 4 + 255) / 256, 256, 0, stream>>>(W1, W1b, 256 * 128);
    cvt_kernel<<<(256 * 256 / 4 + 255) / 256, 256, 0, stream>>>(W2, W2b, 256 * 256);
    cvt_kernel<<<(256 * 256 / 4 + 255) / 256, 256, 0, stream>>>(W3, W3b, 256 * 256);

    // CSR build (cursor doubles as deg histogram)
    hipMemsetAsync(cursor, 0, NN * sizeof(int), stream);
    hist_kernel<<<eblocks, 256, 0, stream>>>(dst, cursor, EE);
    scan_kernel<<<1, 256, 0, stream>>>(cursor, rowptr, cursor);
    bin_kernel<<<eblocks, 256, 0, stream>>>(src, dst, ew, cursor, src_sorted, w_sorted, EE);

    // ---- layer 1: gather x (C=128) -> MFMA W1 + BN1 + ReLU -> h (bf16) ----
    gather_bf<128, true><<<gblocks, 256, 0, stream>>>(xb, rowptr, src_sorted, w_sorted, agg);
    mm_mfma<128, 1><<<dim3(mtiles, 2), 256, 0, stream>>>(
        agg, W1b, b1, g1, be1, m1, v1, hbuf, NN);

    // ---- layer 2: gather h (C=256) -> MFMA W2 + BN2 + ReLU -> h (bf16) ----
    gather_bf<256, true><<<gblocks, 256, 0, stream>>>(hbuf, rowptr, src_sorted, w_sorted, agg);
    mm_mfma<256, 1><<<dim3(mtiles, 2), 256, 0, stream>>>(
        agg, W2b, b2, g2, be2, m2, v2, hbuf, NN);

    // ---- layer 3: gather h (C=256, no weight) -> MFMA W3 + bias -> out (fp32) ----
    gather_bf<256, false><<<gblocks, 256, 0, stream>>>(hbuf, rowptr, src_sorted, nullptr, agg);
    mm_mfma<256, 0><<<dim3(mtiles, 2), 256, 0, stream>>>(
        agg, W3b, b3, nullptr, nullptr, nullptr, nullptr, out, NN);
}

// Round 4
// 789.008 us; speedup vs baseline: 17.3522x; 1.1442x over previous
//
#include <hip/hip_runtime.h>
#include <cstdint>
#include <cstddef>

#define NN 50000
#define EE 1600000

typedef __attribute__((ext_vector_type(8))) short short8;
typedef __attribute__((ext_vector_type(4))) float float4v;

__device__ __forceinline__ float bf2f(unsigned short u) {
    union { unsigned int i; float f; } v; v.i = ((unsigned int)u) << 16; return v.f;
}
__device__ __forceinline__ unsigned short f2bf(float f) {
    union { float f; unsigned int i; } v; v.f = f;
    unsigned int r = v.i + 0x7FFF + ((v.i >> 16) & 1);   // RNE
    return (unsigned short)(r >> 16);
}

// ---------------- fp32 -> bf16 convert ----------------
__global__ __launch_bounds__(256) void cvt_kernel(const float* __restrict__ in,
                                                  unsigned short* __restrict__ out, int n) {
    int i = (blockIdx.x * 256 + threadIdx.x) * 4;
    if (i + 3 >= n) {
        for (int k = i; k < n; k++) out[k] = f2bf(in[k]);
        return;
    }
    float4 v = *(const float4*)(in + i);
    ushort4 o;
    o.x = f2bf(v.x); o.y = f2bf(v.y); o.z = f2bf(v.z); o.w = f2bf(v.w);
    *(ushort4*)(out + i) = o;
}

// ---------------- CSR build: histogram -> scan -> fused bin ----------------
__global__ __launch_bounds__(256) void hist_kernel(const int* __restrict__ dst,
                                                   int* __restrict__ deg, int E) {
    int e = blockIdx.x * 256 + threadIdx.x;
    if (e >= E) return;
    int d = dst[e];
    if ((unsigned)d < NN) atomicAdd(&deg[d], 1);
}

// single block, 256 threads; deg aliases cursor (read-before-write per elem)
__global__ __launch_bounds__(256) void scan_kernel(const int* __restrict__ deg,
                                                   int* __restrict__ rowptr,
                                                   int* __restrict__ cursor) {
    constexpr int CH = (NN + 255) / 256;
    __shared__ int sums[256];
    int t = threadIdx.x;
    int lo = t * CH, hi = min(lo + CH, NN);
    int s = 0;
    for (int i = lo; i < hi; i++) s += deg[i];
    sums[t] = s;
    __syncthreads();
    if (t == 0) {
        int acc = 0;
        for (int i = 0; i < 256; i++) { int v = sums[i]; sums[i] = acc; acc += v; }
    }
    __syncthreads();
    int acc = sums[t];
    for (int i = lo; i < hi; i++) {
        int d = deg[i];
        rowptr[i] = acc;
        cursor[i] = acc;
        acc += d;
    }
    if (hi == NN) rowptr[NN] = acc;
}

// Fused: compute ew from edge_attr inline; store ONE packed 8B record per edge.
__global__ __launch_bounds__(256) void bin_fused(
    const int* __restrict__ src, const int* __restrict__ dst,
    const float* __restrict__ ea, int* __restrict__ cursor,
    int2* __restrict__ recs, int E)
{
    int e = blockIdx.x * 256 + threadIdx.x;
    if (e >= E) return;
    const float4* p = (const float4*)(ea + (size_t)e * 8);
    float4 a = p[0], b = p[1];
    float w = (a.x + a.y + a.z + a.w + b.x + b.y + b.z + b.w) * 0.125f;
    int d = dst[e], s = src[e];
    if ((unsigned)d >= NN || (unsigned)s >= NN) return;
    int pos = atomicAdd(&cursor[d], 1);
    recs[pos] = make_int2(s, __float_as_int(w));
}

// ---------------- gather-aggregate (bf16 in, fp32 acc, bf16 out) ----------------
// One wave per destination node; unroll 4 -> 4 independent row loads in flight.
template <int C, bool HASW>
__global__ __launch_bounds__(256) void gather_bf(
    const unsigned short* __restrict__ h, const int* __restrict__ rowptr,
    const int2* __restrict__ recs, unsigned short* __restrict__ agg)
{
    int node = blockIdx.x * 4 + (threadIdx.x >> 6);
    int lane = threadIdx.x & 63;
    if (node >= NN) return;
    int beg = rowptr[node], end = rowptr[node + 1];

    if (C == 256) {
        float a0 = 0.f, a1 = 0.f, a2 = 0.f, a3 = 0.f;
        int j = beg;
        for (; j + 3 < end; j += 4) {
            int2 r0 = recs[j], r1 = recs[j + 1], r2 = recs[j + 2], r3 = recs[j + 3];
            ushort4 v0 = *(const ushort4*)(h + (size_t)r0.x * 256 + lane * 4);
            ushort4 v1 = *(const ushort4*)(h + (size_t)r1.x * 256 + lane * 4);
            ushort4 v2 = *(const ushort4*)(h + (size_t)r2.x * 256 + lane * 4);
            ushort4 v3 = *(const ushort4*)(h + (size_t)r3.x * 256 + lane * 4);
            float w0 = HASW ? __int_as_float(r0.y) : 1.f;
            float w1 = HASW ? __int_as_float(r1.y) : 1.f;
            float w2 = HASW ? __int_as_float(r2.y) : 1.f;
            float w3 = HASW ? __int_as_float(r3.y) : 1.f;
            a0 += w0 * bf2f(v0.x) + w1 * bf2f(v1.x) + w2 * bf2f(v2.x) + w3 * bf2f(v3.x);
            a1 += w0 * bf2f(v0.y) + w1 * bf2f(v1.y) + w2 * bf2f(v2.y) + w3 * bf2f(v3.y);
            a2 += w0 * bf2f(v0.z) + w1 * bf2f(v1.z) + w2 * bf2f(v2.z) + w3 * bf2f(v3.z);
            a3 += w0 * bf2f(v0.w) + w1 * bf2f(v1.w) + w2 * bf2f(v2.w) + w3 * bf2f(v3.w);
        }
        for (; j < end; j++) {
            int2 r0 = recs[j];
            float w0 = HASW ? __int_as_float(r0.y) : 1.f;
            ushort4 v0 = *(const ushort4*)(h + (size_t)r0.x * 256 + lane * 4);
            a0 += w0 * bf2f(v0.x); a1 += w0 * bf2f(v0.y);
            a2 += w0 * bf2f(v0.z); a3 += w0 * bf2f(v0.w);
        }
        ushort4 o;
        o.x = f2bf(a0); o.y = f2bf(a1); o.z = f2bf(a2); o.w = f2bf(a3);
        *(ushort4*)(agg + (size_t)node * 256 + lane * 4) = o;
    } else {  // C == 128
        float a0 = 0.f, a1 = 0.f;
        int j = beg;
        for (; j + 3 < end; j += 4) {
            int2 r0 = recs[j], r1 = recs[j + 1], r2 = recs[j + 2], r3 = recs[j + 3];
            ushort2 v0 = *(const ushort2*)(h + (size_t)r0.x * 128 + lane * 2);
            ushort2 v1 = *(const ushort2*)(h + (size_t)r1.x * 128 + lane * 2);
            ushort2 v2 = *(const ushort2*)(h + (size_t)r2.x * 128 + lane * 2);
            ushort2 v3 = *(const ushort2*)(h + (size_t)r3.x * 128 + lane * 2);
            float w0 = HASW ? __int_as_float(r0.y) : 1.f;
            float w1 = HASW ? __int_as_float(r1.y) : 1.f;
            float w2 = HASW ? __int_as_float(r2.y) : 1.f;
            float w3 = HASW ? __int_as_float(r3.y) : 1.f;
            a0 += w0 * bf2f(v0.x) + w1 * bf2f(v1.x) + w2 * bf2f(v2.x) + w3 * bf2f(v3.x);
            a1 += w0 * bf2f(v0.y) + w1 * bf2f(v1.y) + w2 * bf2f(v2.y) + w3 * bf2f(v3.y);
        }
        for (; j < end; j++) {
            int2 r0 = recs[j];
            float w0 = HASW ? __int_as_float(r0.y) : 1.f;
            ushort2 v0 = *(const ushort2*)(h + (size_t)r0.x * 128 + lane * 2);
            a0 += w0 * bf2f(v0.x); a1 += w0 * bf2f(v0.y);
        }
        ushort2 o;
        o.x = f2bf(a0); o.y = f2bf(a1);
        *(ushort2*)(agg + (size_t)node * 128 + lane * 2) = o;
    }
}

// ---------------- MFMA GEMM: out[M,256] = A[M,CIN](bf16) @ W[256,CIN](bf16)^T ----
// 256 thr = 4 waves in 2x2; each wave computes 64x64 via 4x4 grid of 16x16x32 MFMA.
template <int CIN, int MODE>
__global__ __launch_bounds__(256) void mm_mfma(
    const unsigned short* __restrict__ A, const unsigned short* __restrict__ W,
    const float* __restrict__ bias,
    const float* __restrict__ gamma, const float* __restrict__ beta,
    const float* __restrict__ mean, const float* __restrict__ var,
    void* __restrict__ out, int M)
{
    const int lane = threadIdx.x & 63;
    const int wave = threadIdx.x >> 6;
    const int quad = lane >> 4;
    const int l16  = lane & 15;
    const int row0 = blockIdx.x * 128 + (wave & 1) * 64;
    const int col0 = blockIdx.y * 128 + (wave >> 1) * 64;

    float4v acc[4][4] = {};

    for (int k0 = 0; k0 < CIN; k0 += 32) {
        const int ka = k0 + quad * 8;
        short8 af[4], bf[4];
        #pragma unroll
        for (int i = 0; i < 4; i++) {
            int r = row0 + i * 16 + l16;
            af[i] = (r < M) ? *(const short8*)(A + (size_t)r * CIN + ka) : (short8)0;
            bf[i] = *(const short8*)(W + (size_t)(col0 + i * 16 + l16) * CIN + ka);
        }
        #pragma unroll
        for (int mi = 0; mi < 4; mi++)
            #pragma unroll
            for (int ni = 0; ni < 4; ni++)
                acc[mi][ni] = __builtin_amdgcn_mfma_f32_16x16x32_bf16(
                    af[mi], bf[ni], acc[mi][ni], 0, 0, 0);
    }

    float cb[4], cmu[4], cinv[4], cbe[4];
    #pragma unroll
    for (int ni = 0; ni < 4; ni++) {
        int gc = col0 + ni * 16 + l16;
        cb[ni] = bias[gc];
        if (MODE == 1) {
            cmu[ni]  = mean[gc];
            cinv[ni] = gamma[gc] * rsqrtf(var[gc] + 1e-5f);
            cbe[ni]  = beta[gc];
        }
    }
    #pragma unroll
    for (int mi = 0; mi < 4; mi++) {
        #pragma unroll
        for (int reg = 0; reg < 4; reg++) {
            int gr = row0 + mi * 16 + quad * 4 + reg;
            if (gr >= M) continue;
            #pragma unroll
            for (int ni = 0; ni < 4; ni++) {
                int gc = col0 + ni * 16 + l16;
                float v = acc[mi][ni][reg] + cb[ni];
                if (MODE == 1) {
                    v = (v - cmu[ni]) * cinv[ni] + cbe[ni];
                    v = fmaxf(v, 0.f);
                    ((unsigned short*)out)[(size_t)gr * 256 + gc] = f2bf(v);
                } else {
                    ((float*)out)[(size_t)gr * 256 + gc] = v;
                }
            }
        }
    }
}

extern "C" void kernel_launch(void* const* d_in, const int* in_sizes, int n_in,
                              void* d_out, int out_size, void* d_ws, size_t ws_size,
                              hipStream_t stream) {
    const float* x   = (const float*)d_in[0];
    const int*   ei  = (const int*)d_in[1];   // [2, E] int32
    const float* ea  = (const float*)d_in[2];
    const float* W1  = (const float*)d_in[3];
    const float* b1  = (const float*)d_in[4];
    const float* g1  = (const float*)d_in[5];
    const float* be1 = (const float*)d_in[6];
    const float* m1  = (const float*)d_in[7];
    const float* v1  = (const float*)d_in[8];
    const float* W2  = (const float*)d_in[9];
    const float* b2  = (const float*)d_in[10];
    const float* g2  = (const float*)d_in[11];
    const float* be2 = (const float*)d_in[12];
    const float* m2  = (const float*)d_in[13];
    const float* v2  = (const float*)d_in[14];
    const float* W3  = (const float*)d_in[15];
    const float* b3  = (const float*)d_in[16];

    const int* src = ei;
    const int* dst = ei + EE;

    // workspace carve-up (256B-aligned segments)
    char* p = (char*)d_ws;
    auto alloc = [&](size_t bytes) { char* r = p; p += (bytes + 255) & ~255ULL; return r; };
    int*            rowptr    = (int*)alloc((NN + 1) * 4);
    int*            cursor    = (int*)alloc(NN * 4);
    int2*           recs      = (int2*)alloc((size_t)EE * 8);
    unsigned short* xb        = (unsigned short*)alloc((size_t)NN * 128 * 2);
    unsigned short* W1b       = (unsigned short*)alloc(256 * 128 * 2);
    unsigned short* W2b       = (unsigned short*)alloc(256 * 256 * 2);
    unsigned short* W3b       = (unsigned short*)alloc(256 * 256 * 2);
    unsigned short* agg       = (unsigned short*)alloc((size_t)NN * 256 * 2);
    unsigned short* hbuf      = (unsigned short*)alloc((size_t)NN * 256 * 2);
    float*          out       = (float*)d_out;

    const int eblocks = (EE + 255) / 256;
    const int gblocks = (NN + 3) / 4;
    const int mtiles  = (NN + 127) / 128;

    // converts
    cvt_kernel<<<(NN * 128 / 4 + 255) / 256, 256, 0, stream>>>(x, xb, NN * 128);
    cvt_kernel<<<(256 * 128 / 4 + 255) / 256, 256, 0, stream>>>(W1, W1b, 256 * 128);
    cvt_kernel<<<(256 * 256 / 4 + 255) / 256, 256, 0, stream>>>(W2, W2b, 256 * 256);
    cvt_kernel<<<(256 * 256 / 4 + 255) / 256, 256, 0, stream>>>(W3, W3b, 256 * 256);

    // CSR build (cursor doubles as deg histogram); ew fused into bin
    hipMemsetAsync(cursor, 0, NN * sizeof(int), stream);
    hist_kernel<<<eblocks, 256, 0, stream>>>(dst, cursor, EE);
    scan_kernel<<<1, 256, 0, stream>>>(cursor, rowptr, cursor);
    bin_fused<<<eblocks, 256, 0, stream>>>(src, dst, ea, cursor, recs, EE);

    // ---- layer 1: gather x (C=128) -> MFMA W1 + BN1 + ReLU -> h (bf16) ----
    gather_bf<128, true><<<gblocks, 256, 0, stream>>>(xb, rowptr, recs, agg);
    mm_mfma<128, 1><<<dim3(mtiles, 2), 256, 0, stream>>>(
        agg, W1b, b1, g1, be1, m1, v1, hbuf, NN);

    // ---- layer 2: gather h (C=256) -> MFMA W2 + BN2 + ReLU -> h (bf16) ----
    gather_bf<256, true><<<gblocks, 256, 0, stream>>>(hbuf, rowptr, recs, agg);
    mm_mfma<256, 1><<<dim3(mtiles, 2), 256, 0, stream>>>(
        agg, W2b, b2, g2, be2, m2, v2, hbuf, NN);

    // ---- layer 3: gather h (C=256, no weight) -> MFMA W3 + bias -> out (fp32) ----
    gather_bf<256, false><<<gblocks, 256, 0, stream>>>(hbuf, rowptr, recs, agg);
    mm_mfma<256, 0><<<dim3(mtiles, 2), 256, 0, stream>>>(
        agg, W3b, b3, nullptr, nullptr, nullptr, nullptr, out, NN);
}

// Round 5
// 660.944 us; speedup vs baseline: 20.7144x; 1.1938x over previous
//
#include <hip/hip_runtime.h>
#include <cstdint>
#include <cstddef>

#define NN 50000
#define EE 1600000
#define SCAN_BLOCKS ((NN + 255) / 256)   // 196

typedef __attribute__((ext_vector_type(8))) short short8;
typedef __attribute__((ext_vector_type(4))) float float4v;

__device__ __forceinline__ float bf2f(unsigned short u) {
    union { unsigned int i; float f; } v; v.i = ((unsigned int)u) << 16; return v.f;
}
__device__ __forceinline__ unsigned short f2bf(float f) {
    union { float f; unsigned int i; } v; v.f = f;
    unsigned int r = v.i + 0x7FFF + ((v.i >> 16) & 1);   // RNE
    return (unsigned short)(r >> 16);
}

// ---------------- fp32 -> bf16 convert (single buffer) ----------------
__global__ __launch_bounds__(256) void cvt_kernel(const float* __restrict__ in,
                                                  unsigned short* __restrict__ out, int n) {
    int i = (blockIdx.x * 256 + threadIdx.x) * 4;
    if (i + 3 >= n) {
        for (int k = i; k < n; k++) out[k] = f2bf(in[k]);
        return;
    }
    float4 v = *(const float4*)(in + i);
    ushort4 o;
    o.x = f2bf(v.x); o.y = f2bf(v.y); o.z = f2bf(v.z); o.w = f2bf(v.w);
    *(ushort4*)(out + i) = o;
}

// fused convert of the 3 weight matrices (one launch)
__global__ __launch_bounds__(256) void cvt_w_kernel(
    const float* __restrict__ w1, unsigned short* __restrict__ o1,   // 32768 elems
    const float* __restrict__ w2, unsigned short* __restrict__ o2,   // 65536 elems
    const float* __restrict__ w3, unsigned short* __restrict__ o3)   // 65536 elems
{
    int i = (blockIdx.x * 256 + threadIdx.x) * 4;
    const float* in; unsigned short* out;
    if (i < 32768) { in = w1; out = o1; }
    else if (i < 32768 + 65536) { in = w2; out = o2; i -= 32768; }
    else { in = w3; out = o3; i -= 32768 + 65536; }
    float4 v = *(const float4*)(in + i);
    ushort4 o;
    o.x = f2bf(v.x); o.y = f2bf(v.y); o.z = f2bf(v.z); o.w = f2bf(v.w);
    *(ushort4*)(out + i) = o;
}

// ---------------- CSR build: histogram -> 3-phase scan -> fused bin ----------------
__global__ __launch_bounds__(256) void hist_kernel(const int* __restrict__ dst,
                                                   int* __restrict__ deg, int E) {
    int e = blockIdx.x * 256 + threadIdx.x;
    if (e >= E) return;
    int d = dst[e];
    if ((unsigned)d < NN) atomicAdd(&deg[d], 1);
}

// phase 1: per-block (256-chunk) sums
__global__ __launch_bounds__(256) void scan1_kernel(const int* __restrict__ deg,
                                                    int* __restrict__ bsum) {
    int i = blockIdx.x * 256 + threadIdx.x;
    int v = (i < NN) ? deg[i] : 0;
    #pragma unroll
    for (int off = 32; off > 0; off >>= 1) v += __shfl_down(v, off, 64);
    __shared__ int ws[4];
    if ((threadIdx.x & 63) == 0) ws[threadIdx.x >> 6] = v;
    __syncthreads();
    if (threadIdx.x == 0) bsum[blockIdx.x] = ws[0] + ws[1] + ws[2] + ws[3];
}

// phase 2: single tiny block scans the SCAN_BLOCKS partials; writes total to rowptr[NN]
__global__ __launch_bounds__(256) void scan2_kernel(const int* __restrict__ bsum,
                                                    int* __restrict__ boff,
                                                    int* __restrict__ rowptr) {
    __shared__ int s[256];
    int t = threadIdx.x;
    int v = (t < SCAN_BLOCKS) ? bsum[t] : 0;
    s[t] = v;
    __syncthreads();
    #pragma unroll
    for (int off = 1; off < 256; off <<= 1) {
        int val = (t >= off) ? s[t - off] : 0;
        __syncthreads();
        s[t] += val;
        __syncthreads();
    }
    if (t < SCAN_BLOCKS) boff[t] = s[t] - v;     // exclusive
    if (t == 255) rowptr[NN] = s[255];           // grand total
}

// phase 3: intra-block exclusive scan + block offset -> rowptr & cursor.
// deg may alias cursor: each thread reads deg[i] (into reg/LDS) before writing cursor[i].
__global__ __launch_bounds__(256) void scan3_kernel(const int* __restrict__ deg,
                                                    const int* __restrict__ boff,
                                                    int* __restrict__ rowptr,
                                                    int* __restrict__ cursor) {
    __shared__ int s[256];
    int t = threadIdx.x;
    int i = blockIdx.x * 256 + t;
    int v = (i < NN) ? deg[i] : 0;
    s[t] = v;
    __syncthreads();
    #pragma unroll
    for (int off = 1; off < 256; off <<= 1) {
        int val = (t >= off) ? s[t - off] : 0;
        __syncthreads();
        s[t] += val;
        __syncthreads();
    }
    int excl = s[t] - v + boff[blockIdx.x];
    if (i < NN) { rowptr[i] = excl; cursor[i] = excl; }
}

// Fused: compute ew from edge_attr inline; store ONE packed 8B record per edge.
__global__ __launch_bounds__(256) void bin_fused(
    const int* __restrict__ src, const int* __restrict__ dst,
    const float* __restrict__ ea, int* __restrict__ cursor,
    int2* __restrict__ recs, int E)
{
    int e = blockIdx.x * 256 + threadIdx.x;
    if (e >= E) return;
    const float4* p = (const float4*)(ea + (size_t)e * 8);
    float4 a = p[0], b = p[1];
    float w = (a.x + a.y + a.z + a.w + b.x + b.y + b.z + b.w) * 0.125f;
    int d = dst[e], s = src[e];
    if ((unsigned)d >= NN || (unsigned)s >= NN) return;
    int pos = atomicAdd(&cursor[d], 1);
    recs[pos] = make_int2(s, __float_as_int(w));
}

// ---------------- gather-aggregate (bf16 in, fp32 acc, bf16 out) ----------------
// One wave per destination node; unroll 8 -> 8 independent row loads in flight.
template <int C, bool HASW>
__global__ __launch_bounds__(256) void gather_bf(
    const unsigned short* __restrict__ h, const int* __restrict__ rowptr,
    const int2* __restrict__ recs, unsigned short* __restrict__ agg)
{
    int node = blockIdx.x * 4 + (threadIdx.x >> 6);
    int lane = threadIdx.x & 63;
    if (node >= NN) return;
    int beg = rowptr[node], end = rowptr[node + 1];

    if (C == 256) {
        float a0 = 0.f, a1 = 0.f, a2 = 0.f, a3 = 0.f;
        int j = beg;
        for (; j + 7 < end; j += 8) {
            int2 r[8]; ushort4 v[8];
            #pragma unroll
            for (int u = 0; u < 8; u++) r[u] = recs[j + u];
            #pragma unroll
            for (int u = 0; u < 8; u++)
                v[u] = *(const ushort4*)(h + (size_t)r[u].x * 256 + lane * 4);
            #pragma unroll
            for (int u = 0; u < 8; u++) {
                float w = HASW ? __int_as_float(r[u].y) : 1.f;
                a0 += w * bf2f(v[u].x);
                a1 += w * bf2f(v[u].y);
                a2 += w * bf2f(v[u].z);
                a3 += w * bf2f(v[u].w);
            }
        }
        for (; j < end; j++) {
            int2 r0 = recs[j];
            float w0 = HASW ? __int_as_float(r0.y) : 1.f;
            ushort4 v0 = *(const ushort4*)(h + (size_t)r0.x * 256 + lane * 4);
            a0 += w0 * bf2f(v0.x); a1 += w0 * bf2f(v0.y);
            a2 += w0 * bf2f(v0.z); a3 += w0 * bf2f(v0.w);
        }
        ushort4 o;
        o.x = f2bf(a0); o.y = f2bf(a1); o.z = f2bf(a2); o.w = f2bf(a3);
        *(ushort4*)(agg + (size_t)node * 256 + lane * 4) = o;
    } else {  // C == 128
        float a0 = 0.f, a1 = 0.f;
        int j = beg;
        for (; j + 7 < end; j += 8) {
            int2 r[8]; ushort2 v[8];
            #pragma unroll
            for (int u = 0; u < 8; u++) r[u] = recs[j + u];
            #pragma unroll
            for (int u = 0; u < 8; u++)
                v[u] = *(const ushort2*)(h + (size_t)r[u].x * 128 + lane * 2);
            #pragma unroll
            for (int u = 0; u < 8; u++) {
                float w = HASW ? __int_as_float(r[u].y) : 1.f;
                a0 += w * bf2f(v[u].x);
                a1 += w * bf2f(v[u].y);
            }
        }
        for (; j < end; j++) {
            int2 r0 = recs[j];
            float w0 = HASW ? __int_as_float(r0.y) : 1.f;
            ushort2 v0 = *(const ushort2*)(h + (size_t)r0.x * 128 + lane * 2);
            a0 += w0 * bf2f(v0.x); a1 += w0 * bf2f(v0.y);
        }
        ushort2 o;
        o.x = f2bf(a0); o.y = f2bf(a1);
        *(ushort2*)(agg + (size_t)node * 128 + lane * 2) = o;
    }
}

// ---------------- MFMA GEMM: out[M,256] = A[M,CIN](bf16) @ W[256,CIN](bf16)^T ----
// 256 thr = 4 waves in 2x2; each wave computes 64x64 via 4x4 grid of 16x16x32 MFMA.
template <int CIN, int MODE>
__global__ __launch_bounds__(256) void mm_mfma(
    const unsigned short* __restrict__ A, const unsigned short* __restrict__ W,
    const float* __restrict__ bias,
    const float* __restrict__ gamma, const float* __restrict__ beta,
    const float* __restrict__ mean, const float* __restrict__ var,
    void* __restrict__ out, int M)
{
    const int lane = threadIdx.x & 63;
    const int wave = threadIdx.x >> 6;
    const int quad = lane >> 4;
    const int l16  = lane & 15;
    const int row0 = blockIdx.x * 128 + (wave & 1) * 64;
    const int col0 = blockIdx.y * 128 + (wave >> 1) * 64;

    float4v acc[4][4] = {};

    for (int k0 = 0; k0 < CIN; k0 += 32) {
        const int ka = k0 + quad * 8;
        short8 af[4], bf[4];
        #pragma unroll
        for (int i = 0; i < 4; i++) {
            int r = row0 + i * 16 + l16;
            af[i] = (r < M) ? *(const short8*)(A + (size_t)r * CIN + ka) : (short8)0;
            bf[i] = *(const short8*)(W + (size_t)(col0 + i * 16 + l16) * CIN + ka);
        }
        #pragma unroll
        for (int mi = 0; mi < 4; mi++)
            #pragma unroll
            for (int ni = 0; ni < 4; ni++)
                acc[mi][ni] = __builtin_amdgcn_mfma_f32_16x16x32_bf16(
                    af[mi], bf[ni], acc[mi][ni], 0, 0, 0);
    }

    float cb[4], cmu[4], cinv[4], cbe[4];
    #pragma unroll
    for (int ni = 0; ni < 4; ni++) {
        int gc = col0 + ni * 16 + l16;
        cb[ni] = bias[gc];
        if (MODE == 1) {
            cmu[ni]  = mean[gc];
            cinv[ni] = gamma[gc] * rsqrtf(var[gc] + 1e-5f);
            cbe[ni]  = beta[gc];
        }
    }
    #pragma unroll
    for (int mi = 0; mi < 4; mi++) {
        #pragma unroll
        for (int reg = 0; reg < 4; reg++) {
            int gr = row0 + mi * 16 + quad * 4 + reg;
            if (gr >= M) continue;
            #pragma unroll
            for (int ni = 0; ni < 4; ni++) {
                int gc = col0 + ni * 16 + l16;
                float v = acc[mi][ni][reg] + cb[ni];
                if (MODE == 1) {
                    v = (v - cmu[ni]) * cinv[ni] + cbe[ni];
                    v = fmaxf(v, 0.f);
                    ((unsigned short*)out)[(size_t)gr * 256 + gc] = f2bf(v);
                } else {
                    ((float*)out)[(size_t)gr * 256 + gc] = v;
                }
            }
        }
    }
}

extern "C" void kernel_launch(void* const* d_in, const int* in_sizes, int n_in,
                              void* d_out, int out_size, void* d_ws, size_t ws_size,
                              hipStream_t stream) {
    const float* x   = (const float*)d_in[0];
    const int*   ei  = (const int*)d_in[1];   // [2, E] int32
    const float* ea  = (const float*)d_in[2];
    const float* W1  = (const float*)d_in[3];
    const float* b1  = (const float*)d_in[4];
    const float* g1  = (const float*)d_in[5];
    const float* be1 = (const float*)d_in[6];
    const float* m1  = (const float*)d_in[7];
    const float* v1  = (const float*)d_in[8];
    const float* W2  = (const float*)d_in[9];
    const float* b2  = (const float*)d_in[10];
    const float* g2  = (const float*)d_in[11];
    const float* be2 = (const float*)d_in[12];
    const float* m2  = (const float*)d_in[13];
    const float* v2  = (const float*)d_in[14];
    const float* W3  = (const float*)d_in[15];
    const float* b3  = (const float*)d_in[16];

    const int* src = ei;
    const int* dst = ei + EE;

    // workspace carve-up (256B-aligned segments)
    char* p = (char*)d_ws;
    auto alloc = [&](size_t bytes) { char* r = p; p += (bytes + 255) & ~255ULL; return r; };
    int*            rowptr    = (int*)alloc((NN + 1) * 4);
    int*            cursor    = (int*)alloc(NN * 4);
    int*            bsum      = (int*)alloc(SCAN_BLOCKS * 4);
    int*            boff      = (int*)alloc(SCAN_BLOCKS * 4);
    int2*           recs      = (int2*)alloc((size_t)EE * 8);
    unsigned short* xb        = (unsigned short*)alloc((size_t)NN * 128 * 2);
    unsigned short* W1b       = (unsigned short*)alloc(256 * 128 * 2);
    unsigned short* W2b       = (unsigned short*)alloc(256 * 256 * 2);
    unsigned short* W3b       = (unsigned short*)alloc(256 * 256 * 2);
    unsigned short* agg       = (unsigned short*)alloc((size_t)NN * 256 * 2);
    unsigned short* hbuf      = (unsigned short*)alloc((size_t)NN * 256 * 2);
    float*          out       = (float*)d_out;

    const int eblocks = (EE + 255) / 256;
    const int gblocks = (NN + 3) / 4;
    const int mtiles  = (NN + 127) / 128;

    // converts
    cvt_kernel<<<(NN * 128 / 4 + 255) / 256, 256, 0, stream>>>(x, xb, NN * 128);
    cvt_w_kernel<<<(32768 + 65536 + 65536) / 4 / 256, 256, 0, stream>>>(
        W1, W1b, W2, W2b, W3, W3b);

    // CSR build: hist -> 3-phase scan -> fused bin (cursor doubles as deg histogram)
    hipMemsetAsync(cursor, 0, NN * sizeof(int), stream);
    hist_kernel<<<eblocks, 256, 0, stream>>>(dst, cursor, EE);
    scan1_kernel<<<SCAN_BLOCKS, 256, 0, stream>>>(cursor, bsum);
    scan2_kernel<<<1, 256, 0, stream>>>(bsum, boff, rowptr);
    scan3_kernel<<<SCAN_BLOCKS, 256, 0, stream>>>(cursor, boff, rowptr, cursor);
    bin_fused<<<eblocks, 256, 0, stream>>>(src, dst, ea, cursor, recs, EE);

    // ---- layer 1: gather x (C=128) -> MFMA W1 + BN1 + ReLU -> h (bf16) ----
    gather_bf<128, true><<<gblocks, 256, 0, stream>>>(xb, rowptr, recs, agg);
    mm_mfma<128, 1><<<dim3(mtiles, 2), 256, 0, stream>>>(
        agg, W1b, b1, g1, be1, m1, v1, hbuf, NN);

    // ---- layer 2: gather h (C=256) -> MFMA W2 + BN2 + ReLU -> h (bf16) ----
    gather_bf<256, true><<<gblocks, 256, 0, stream>>>(hbuf, rowptr, recs, agg);
    mm_mfma<256, 1><<<dim3(mtiles, 2), 256, 0, stream>>>(
        agg, W2b, b2, g2, be2, m2, v2, hbuf, NN);

    // ---- layer 3: gather h (C=256, no weight) -> MFMA W3 + bias -> out (fp32) ----
    gather_bf<256, false><<<gblocks, 256, 0, stream>>>(hbuf, rowptr, recs, agg);
    mm_mfma<256, 0><<<dim3(mtiles, 2), 256, 0, stream>>>(
        agg, W3b, b3, nullptr, nullptr, nullptr, nullptr, out, NN);
}

// Round 6
// 649.853 us; speedup vs baseline: 21.0679x; 1.0171x over previous
//
#include <hip/hip_runtime.h>
#include <cstdint>
#include <cstddef>

#define NN 50000
#define EE 1600000
#define SCAN_BLOCKS ((NN + 255) / 256)   // 196

typedef __attribute__((ext_vector_type(8))) short short8;
typedef __attribute__((ext_vector_type(8))) unsigned short ushort8;
typedef __attribute__((ext_vector_type(4))) float float4v;

__device__ __forceinline__ float bf2f(unsigned short u) {
    union { unsigned int i; float f; } v; v.i = ((unsigned int)u) << 16; return v.f;
}
__device__ __forceinline__ unsigned short f2bf(float f) {
    union { float f; unsigned int i; } v; v.f = f;
    unsigned int r = v.i + 0x7FFF + ((v.i >> 16) & 1);   // RNE
    return (unsigned short)(r >> 16);
}

// ---------------- fp32 -> bf16 convert ----------------
__global__ __launch_bounds__(256) void cvt_kernel(const float* __restrict__ in,
                                                  unsigned short* __restrict__ out, int n) {
    int i = (blockIdx.x * 256 + threadIdx.x) * 4;
    if (i + 3 >= n) {
        for (int k = i; k < n; k++) out[k] = f2bf(in[k]);
        return;
    }
    float4 v = *(const float4*)(in + i);
    ushort4 o;
    o.x = f2bf(v.x); o.y = f2bf(v.y); o.z = f2bf(v.z); o.w = f2bf(v.w);
    *(ushort4*)(out + i) = o;
}

// fused convert of the 3 weight matrices (one launch)
__global__ __launch_bounds__(256) void cvt_w_kernel(
    const float* __restrict__ w1, unsigned short* __restrict__ o1,   // 32768
    const float* __restrict__ w2, unsigned short* __restrict__ o2,   // 65536
    const float* __restrict__ w3, unsigned short* __restrict__ o3)   // 65536
{
    int i = (blockIdx.x * 256 + threadIdx.x) * 4;
    const float* in; unsigned short* out;
    if (i < 32768) { in = w1; out = o1; }
    else if (i < 32768 + 65536) { in = w2; out = o2; i -= 32768; }
    else { in = w3; out = o3; i -= 32768 + 65536; }
    float4 v = *(const float4*)(in + i);
    ushort4 o;
    o.x = f2bf(v.x); o.y = f2bf(v.y); o.z = f2bf(v.z); o.w = f2bf(v.w);
    *(ushort4*)(out + i) = o;
}

// ---------------- CSR build: histogram -> 3-phase scan -> fused bin ----------------
__global__ __launch_bounds__(256) void hist_kernel(const int* __restrict__ dst,
                                                   int* __restrict__ deg, int E) {
    int e = blockIdx.x * 256 + threadIdx.x;
    if (e >= E) return;
    int d = dst[e];
    if ((unsigned)d < NN) atomicAdd(&deg[d], 1);
}

__global__ __launch_bounds__(256) void scan1_kernel(const int* __restrict__ deg,
                                                    int* __restrict__ bsum) {
    int i = blockIdx.x * 256 + threadIdx.x;
    int v = (i < NN) ? deg[i] : 0;
    #pragma unroll
    for (int off = 32; off > 0; off >>= 1) v += __shfl_down(v, off, 64);
    __shared__ int ws[4];
    if ((threadIdx.x & 63) == 0) ws[threadIdx.x >> 6] = v;
    __syncthreads();
    if (threadIdx.x == 0) bsum[blockIdx.x] = ws[0] + ws[1] + ws[2] + ws[3];
}

__global__ __launch_bounds__(256) void scan2_kernel(const int* __restrict__ bsum,
                                                    int* __restrict__ boff,
                                                    int* __restrict__ rowptr) {
    __shared__ int s[256];
    int t = threadIdx.x;
    int v = (t < SCAN_BLOCKS) ? bsum[t] : 0;
    s[t] = v;
    __syncthreads();
    #pragma unroll
    for (int off = 1; off < 256; off <<= 1) {
        int val = (t >= off) ? s[t - off] : 0;
        __syncthreads();
        s[t] += val;
        __syncthreads();
    }
    if (t < SCAN_BLOCKS) boff[t] = s[t] - v;
    if (t == 255) rowptr[NN] = s[255];
}

__global__ __launch_bounds__(256) void scan3_kernel(const int* __restrict__ deg,
                                                    const int* __restrict__ boff,
                                                    int* __restrict__ rowptr,
                                                    int* __restrict__ cursor) {
    __shared__ int s[256];
    int t = threadIdx.x;
    int i = blockIdx.x * 256 + t;
    int v = (i < NN) ? deg[i] : 0;
    s[t] = v;
    __syncthreads();
    #pragma unroll
    for (int off = 1; off < 256; off <<= 1) {
        int val = (t >= off) ? s[t - off] : 0;
        __syncthreads();
        s[t] += val;
        __syncthreads();
    }
    int excl = s[t] - v + boff[blockIdx.x];
    if (i < NN) { rowptr[i] = excl; cursor[i] = excl; }
}

// Fused: ew from edge_attr inline; ONE packed 4B record/edge: src(lo16) | bf16 w(hi16)
__global__ __launch_bounds__(256) void bin_fused(
    const int* __restrict__ src, const int* __restrict__ dst,
    const float* __restrict__ ea, int* __restrict__ cursor,
    unsigned int* __restrict__ recs, int E)
{
    int e = blockIdx.x * 256 + threadIdx.x;
    if (e >= E) return;
    const float4* p = (const float4*)(ea + (size_t)e * 8);
    float4 a = p[0], b = p[1];
    float w = (a.x + a.y + a.z + a.w + b.x + b.y + b.z + b.w) * 0.125f;
    int d = dst[e], s = src[e];
    if ((unsigned)d >= NN || (unsigned)s >= NN) return;
    int pos = atomicAdd(&cursor[d], 1);
    recs[pos] = (unsigned int)s | ((unsigned int)f2bf(w) << 16);
}

// ---------------- gather-aggregate (bf16 in, fp32 acc, bf16 out) ----------------
// One wave per node. C=256: half-wave (32 ln x 16B) per edge row -> 2 edges/load.
// C=128: quarter-wave (16 ln x 16B) per edge row -> 4 edges/load.
template <int C, bool HASW>
__global__ __launch_bounds__(256) void gather_bf(
    const unsigned short* __restrict__ h, const int* __restrict__ rowptr,
    const unsigned int* __restrict__ recs, unsigned short* __restrict__ agg)
{
    int node = blockIdx.x * 4 + (threadIdx.x >> 6);
    int lane = threadIdx.x & 63;
    if (node >= NN) return;
    int beg = rowptr[node], end = rowptr[node + 1];

    float a[8] = {0.f, 0.f, 0.f, 0.f, 0.f, 0.f, 0.f, 0.f};

    if (C == 256) {
        const int half = lane >> 5;      // which edge of the pair
        const int l32  = lane & 31;      // 16B segment within row
        int j = beg;
        for (; j + 16 <= end; j += 16) {   // 8 loads x 2 edges
            unsigned int r[8]; ushort8 v[8];
            #pragma unroll
            for (int u = 0; u < 8; u++) r[u] = recs[j + 2 * u + half];
            #pragma unroll
            for (int u = 0; u < 8; u++)
                v[u] = *(const ushort8*)(h + (size_t)(r[u] & 0xFFFF) * 256 + l32 * 8);
            #pragma unroll
            for (int u = 0; u < 8; u++) {
                float w = HASW ? bf2f((unsigned short)(r[u] >> 16)) : 1.f;
                #pragma unroll
                for (int k = 0; k < 8; k++) a[k] += w * bf2f(v[u][k]);
            }
        }
        for (; j < end; j += 2) {          // masked tail, 2 edges/step
            int idx = j + half;
            unsigned int r = recs[idx < end ? idx : end - 1];
            float w = (idx < end) ? (HASW ? bf2f((unsigned short)(r >> 16)) : 1.f) : 0.f;
            ushort8 v = *(const ushort8*)(h + (size_t)(r & 0xFFFF) * 256 + l32 * 8);
            #pragma unroll
            for (int k = 0; k < 8; k++) a[k] += w * bf2f(v[k]);
        }
        #pragma unroll
        for (int k = 0; k < 8; k++) a[k] += __shfl_xor(a[k], 32, 64);
        if (half == 0) {
            ushort8 o;
            #pragma unroll
            for (int k = 0; k < 8; k++) o[k] = f2bf(a[k]);
            *(ushort8*)(agg + (size_t)node * 256 + l32 * 8) = o;
        }
    } else {  // C == 128
        const int quar = lane >> 4;      // which edge of the quad
        const int l16  = lane & 15;
        int j = beg;
        for (; j + 16 <= end; j += 16) {   // 4 loads x 4 edges
            unsigned int r[4]; ushort8 v[4];
            #pragma unroll
            for (int u = 0; u < 4; u++) r[u] = recs[j + 4 * u + quar];
            #pragma unroll
            for (int u = 0; u < 4; u++)
                v[u] = *(const ushort8*)(h + (size_t)(r[u] & 0xFFFF) * 128 + l16 * 8);
            #pragma unroll
            for (int u = 0; u < 4; u++) {
                float w = HASW ? bf2f((unsigned short)(r[u] >> 16)) : 1.f;
                #pragma unroll
                for (int k = 0; k < 8; k++) a[k] += w * bf2f(v[u][k]);
            }
        }
        for (; j < end; j += 4) {          // masked tail, 4 edges/step
            int idx = j + quar;
            unsigned int r = recs[idx < end ? idx : end - 1];
            float w = (idx < end) ? (HASW ? bf2f((unsigned short)(r >> 16)) : 1.f) : 0.f;
            ushort8 v = *(const ushort8*)(h + (size_t)(r & 0xFFFF) * 128 + l16 * 8);
            #pragma unroll
            for (int k = 0; k < 8; k++) a[k] += w * bf2f(v[k]);
        }
        #pragma unroll
        for (int k = 0; k < 8; k++) {
            a[k] += __shfl_xor(a[k], 16, 64);
            a[k] += __shfl_xor(a[k], 32, 64);
        }
        if (quar == 0) {
            ushort8 o;
            #pragma unroll
            for (int k = 0; k < 8; k++) o[k] = f2bf(a[k]);
            *(ushort8*)(agg + (size_t)node * 128 + l16 * 8) = o;
        }
    }
}

// ---------------- MFMA GEMM: out[M,256] = A[M,CIN](bf16) @ W[256,CIN](bf16)^T ----
template <int CIN, int MODE>
__global__ __launch_bounds__(256) void mm_mfma(
    const unsigned short* __restrict__ A, const unsigned short* __restrict__ W,
    const float* __restrict__ bias,
    const float* __restrict__ gamma, const float* __restrict__ beta,
    const float* __restrict__ mean, const float* __restrict__ var,
    void* __restrict__ out, int M)
{
    const int lane = threadIdx.x & 63;
    const int wave = threadIdx.x >> 6;
    const int quad = lane >> 4;
    const int l16  = lane & 15;
    const int row0 = blockIdx.x * 128 + (wave & 1) * 64;
    const int col0 = blockIdx.y * 128 + (wave >> 1) * 64;

    float4v acc[4][4] = {};

    for (int k0 = 0; k0 < CIN; k0 += 32) {
        const int ka = k0 + quad * 8;
        short8 af[4], bf[4];
        #pragma unroll
        for (int i = 0; i < 4; i++) {
            int r = row0 + i * 16 + l16;
            af[i] = (r < M) ? *(const short8*)(A + (size_t)r * CIN + ka) : (short8)0;
            bf[i] = *(const short8*)(W + (size_t)(col0 + i * 16 + l16) * CIN + ka);
        }
        #pragma unroll
        for (int mi = 0; mi < 4; mi++)
            #pragma unroll
            for (int ni = 0; ni < 4; ni++)
                acc[mi][ni] = __builtin_amdgcn_mfma_f32_16x16x32_bf16(
                    af[mi], bf[ni], acc[mi][ni], 0, 0, 0);
    }

    float cb[4], cmu[4], cinv[4], cbe[4];
    #pragma unroll
    for (int ni = 0; ni < 4; ni++) {
        int gc = col0 + ni * 16 + l16;
        cb[ni] = bias[gc];
        if (MODE == 1) {
            cmu[ni]  = mean[gc];
            cinv[ni] = gamma[gc] * rsqrtf(var[gc] + 1e-5f);
            cbe[ni]  = beta[gc];
        }
    }
    #pragma unroll
    for (int mi = 0; mi < 4; mi++) {
        #pragma unroll
        for (int reg = 0; reg < 4; reg++) {
            int gr = row0 + mi * 16 + quad * 4 + reg;
            if (gr >= M) continue;
            #pragma unroll
            for (int ni = 0; ni < 4; ni++) {
                int gc = col0 + ni * 16 + l16;
                float v = acc[mi][ni][reg] + cb[ni];
                if (MODE == 1) {
                    v = (v - cmu[ni]) * cinv[ni] + cbe[ni];
                    v = fmaxf(v, 0.f);
                    ((unsigned short*)out)[(size_t)gr * 256 + gc] = f2bf(v);
                } else {
                    ((float*)out)[(size_t)gr * 256 + gc] = v;
                }
            }
        }
    }
}

extern "C" void kernel_launch(void* const* d_in, const int* in_sizes, int n_in,
                              void* d_out, int out_size, void* d_ws, size_t ws_size,
                              hipStream_t stream) {
    const float* x   = (const float*)d_in[0];
    const int*   ei  = (const int*)d_in[1];   // [2, E] int32
    const float* ea  = (const float*)d_in[2];
    const float* W1  = (const float*)d_in[3];
    const float* b1  = (const float*)d_in[4];
    const float* g1  = (const float*)d_in[5];
    const float* be1 = (const float*)d_in[6];
    const float* m1  = (const float*)d_in[7];
    const float* v1  = (const float*)d_in[8];
    const float* W2  = (const float*)d_in[9];
    const float* b2  = (const float*)d_in[10];
    const float* g2  = (const float*)d_in[11];
    const float* be2 = (const float*)d_in[12];
    const float* m2  = (const float*)d_in[13];
    const float* v2  = (const float*)d_in[14];
    const float* W3  = (const float*)d_in[15];
    const float* b3  = (const float*)d_in[16];

    const int* src = ei;
    const int* dst = ei + EE;

    // workspace carve-up (256B-aligned segments)
    char* p = (char*)d_ws;
    auto alloc = [&](size_t bytes) { char* r = p; p += (bytes + 255) & ~255ULL; return r; };
    int*            rowptr    = (int*)alloc((NN + 1) * 4);
    int*            cursor    = (int*)alloc(NN * 4);
    int*            bsum      = (int*)alloc(SCAN_BLOCKS * 4);
    int*            boff      = (int*)alloc(SCAN_BLOCKS * 4);
    unsigned int*   recs      = (unsigned int*)alloc((size_t)EE * 4);
    unsigned short* xb        = (unsigned short*)alloc((size_t)NN * 128 * 2);
    unsigned short* W1b       = (unsigned short*)alloc(256 * 128 * 2);
    unsigned short* W2b       = (unsigned short*)alloc(256 * 256 * 2);
    unsigned short* W3b       = (unsigned short*)alloc(256 * 256 * 2);
    unsigned short* agg       = (unsigned short*)alloc((size_t)NN * 256 * 2);
    unsigned short* hbuf      = (unsigned short*)alloc((size_t)NN * 256 * 2);
    float*          out       = (float*)d_out;

    const int eblocks = (EE + 255) / 256;
    const int gblocks = (NN + 3) / 4;
    const int mtiles  = (NN + 127) / 128;

    // converts
    cvt_kernel<<<(NN * 128 / 4 + 255) / 256, 256, 0, stream>>>(x, xb, NN * 128);
    cvt_w_kernel<<<(32768 + 65536 + 65536) / 4 / 256, 256, 0, stream>>>(
        W1, W1b, W2, W2b, W3, W3b);

    // CSR build: hist -> 3-phase scan -> fused bin (cursor doubles as histogram)
    hipMemsetAsync(cursor, 0, NN * sizeof(int), stream);
    hist_kernel<<<eblocks, 256, 0, stream>>>(dst, cursor, EE);
    scan1_kernel<<<SCAN_BLOCKS, 256, 0, stream>>>(cursor, bsum);
    scan2_kernel<<<1, 256, 0, stream>>>(bsum, boff, rowptr);
    scan3_kernel<<<SCAN_BLOCKS, 256, 0, stream>>>(cursor, boff, rowptr, cursor);
    bin_fused<<<eblocks, 256, 0, stream>>>(src, dst, ea, cursor, recs, EE);

    // ---- layer 1: gather x (C=128) -> MFMA W1 + BN1 + ReLU -> h (bf16) ----
    gather_bf<128, true><<<gblocks, 256, 0, stream>>>(xb, rowptr, recs, agg);
    mm_mfma<128, 1><<<dim3(mtiles, 2), 256, 0, stream>>>(
        agg, W1b, b1, g1, be1, m1, v1, hbuf, NN);

    // ---- layer 2: gather h (C=256) -> MFMA W2 + BN2 + ReLU -> h (bf16) ----
    gather_bf<256, true><<<gblocks, 256, 0, stream>>>(hbuf, rowptr, recs, agg);
    mm_mfma<256, 1><<<dim3(mtiles, 2), 256, 0, stream>>>(
        agg, W2b, b2, g2, be2, m2, v2, hbuf, NN);

    // ---- layer 3: gather h (C=256, no weight) -> MFMA W3 + bias -> out (fp32) ----
    gather_bf<256, false><<<gblocks, 256, 0, stream>>>(hbuf, rowptr, recs, agg);
    mm_mfma<256, 0><<<dim3(mtiles, 2), 256, 0, stream>>>(
        agg, W3b, b3, nullptr, nullptr, nullptr, nullptr, out, NN);
}